// Round 2
// baseline (1119.658 us; speedup 1.0000x reference)
//
#include <hip/hip_runtime.h>

// EvolvedNet: 32-node graph relaxation, 128 edges applied sequentially per
// sweep, 32 sweeps, batched over 524288 independent elements.
//
// R1: VALU-bound at 91%, ~49.5 VALU cy/wave-edge, of which ~35 cy is the two
// transcendentals (v_exp_f32 + v_rcp_f32) in tanh. R2 change: wave-collective
// saturation skip — for |x| >= 10, f32 tanh == +-1.0 EXACTLY for both the
// reference and our exp2 formula (checked at the rounding level), so when all
// 64 lanes are saturated we substitute copysign(1,x) and skip both
// transcendentals. __all() is wave-uniform -> s_cbranch, no exec masking.

#define N_NODES   32
#define N_INPUTS  8
#define N_OUTPUTS 4
#define N_EDGES   128
#define BATCH     524288
#define BLOCK     256

// 2 * log2(e)
#define TWO_LOG2E 2.88539008177792681472f
// |x| >= 10  <=>  |x * TWO_LOG2E| >= SAT_T. At |x|>=10 both ref f32 tanh and
// our 1-2*rcp(1+exp2(x*K)) round to exactly +-1.0 (tanh(9.2) already rounds
// to 1.0f; 10 leaves margin).
#define SAT_T 28.8539008f

__device__ __forceinline__ float tanh_from_exp2(float x_times_k) {
    // expects x_times_k = x * 2*log2(e); tanh(x) = 1 - 2/(1+2^(x*2log2e))
    const float u = __builtin_amdgcn_exp2f(x_times_k);
    return 1.0f - 2.0f * __builtin_amdgcn_rcpf(1.0f + u);
}

__global__ __launch_bounds__(BLOCK)
void EvolvedNet_80032420593868_kernel(const float* __restrict__ x,
                                      const float* __restrict__ w,
                                      const int*   __restrict__ src,
                                      const int*   __restrict__ dst,
                                      float*       __restrict__ out) {
    // vals[node][tid]: per-thread column; node index uniform across the wave
    // -> address = node_off + tid*4 -> banks 0..31 twice across 64 lanes (free).
    __shared__ float vals[N_NODES][BLOCK];

    const int tid = threadIdx.x;
    const int b   = blockIdx.x * BLOCK + tid;

    // init: inputs into nodes 0..7, zeros elsewhere. Coalesced reads.
#pragma unroll
    for (int n = 0; n < N_INPUTS; ++n)
        vals[n][tid] = x[n * BATCH + b];
#pragma unroll
    for (int n = N_INPUTS; n < N_NODES; ++n)
        vals[n][tid] = 0.0f;

    // No __syncthreads needed anywhere: each thread touches only its own
    // column; within-thread LDS ops are ordered by the in-order DS pipe.

    for (int sweep = 0; sweep < N_NODES; ++sweep) {
#pragma unroll 8
        for (int e = 0; e < N_EDGES; ++e) {
            const int   s  = src[e];       // uniform -> s_load
            const int   d  = dst[e];       // uniform -> s_load
            const float wk = w[e] * TWO_LOG2E;
            const float v  = vals[s][tid];
            const float a  = v * wk;

            float t;
            // Wave-uniform predicate -> scalar branch (s_cbranch), no exec
            // masking. Numerically identical: at |a|>=SAT_T both paths give
            // exactly +-1.0f.
            if (__all(__builtin_fabsf(a) >= SAT_T)) {
                t = __builtin_copysignf(1.0f, a);   // v_bfi_b32, 1 op
            } else {
                t = tanh_from_exp2(a);
            }
            vals[d][tid] += t;             // sequential semantics preserved
        }
    }

    // outputs: tanh(vals[28..31]); out is [N_OUTPUTS][BATCH] flat.
#pragma unroll
    for (int o = 0; o < N_OUTPUTS; ++o) {
        const float v = vals[N_NODES - N_OUTPUTS + o][tid];
        out[o * BATCH + b] = tanh_from_exp2(v * TWO_LOG2E);
    }
}

extern "C" void kernel_launch(void* const* d_in, const int* in_sizes, int n_in,
                              void* d_out, int out_size, void* d_ws, size_t ws_size,
                              hipStream_t stream) {
    const float* x   = (const float*)d_in[0];
    const float* w   = (const float*)d_in[1];
    const int*   src = (const int*)d_in[2];
    const int*   dst = (const int*)d_in[3];
    float*       out = (float*)d_out;

    const int grid = BATCH / BLOCK;  // 2048 blocks, exact
    EvolvedNet_80032420593868_kernel<<<grid, BLOCK, 0, stream>>>(x, w, src, dst, out);
}

// Round 3
// 760.017 us; speedup vs baseline: 1.4732x; 1.4732x over previous
//
#include <hip/hip_runtime.h>

// EvolvedNet: 32-node graph relaxation, 128 edges applied sequentially per
// sweep, 32 sweeps, batched over 524288 independent elements.
//
// R1: 743us, VALU-bound (91%), ~49.5 VALU cy/wave-edge.
// R2: wave-uniform saturation branch REGRESSED (1230us, VALUBusy 57%) —
//     per-edge cmp+branch fragmented the loop, exposed the dependent chain.
//     Reverted; inner loop must stay branch-free straight-line code.
// R3: (a) pre-kernel hoists per-edge uniform work (wk=w*2log2e, node byte
//     offsets) into d_ws; main kernel forces them scalar via readfirstlane
//     -> per-edge VALU is just addr-add + mul + exp + add + rcp + fma + acc.
//     (b) 2 batch elements per thread as float2: ds_read_b64, pk-f32 ALU,
//     addr/scalar work amortized 2x. Transcendentals unchanged per element.

#define N_NODES   32
#define N_INPUTS  8
#define N_OUTPUTS 4
#define N_EDGES   128
#define BATCH     524288
#define BLOCK     64                 // threads per block (1 wave)
#define EPT       2                  // batch elements per thread
#define TILE      (BLOCK * EPT)      // 128 elements per block

// 2 * log2(e)
#define TWO_LOG2E 2.88539008177792681472f

typedef float f32x2 __attribute__((ext_vector_type(2)));

__device__ __forceinline__ float sread_f(const float* p) {
    return __int_as_float(__builtin_amdgcn_readfirstlane(__float_as_int(*p)));
}

// Pre-kernel: per-edge uniform precompute into d_ws (graph-capture safe,
// deterministic, runs every call).
__global__ void EvolvedNet_prep(const float* __restrict__ w,
                                const int*   __restrict__ src,
                                const int*   __restrict__ dst,
                                int* __restrict__ soff, int* __restrict__ doff,
                                float* __restrict__ wk) {
    const int e = threadIdx.x;
    if (e < N_EDGES) {
        soff[e] = src[e] * BLOCK;        // node row offset in f32x2 elements
        doff[e] = dst[e] * BLOCK;
        wk[e]   = w[e] * TWO_LOG2E;      // identical f32 op as before -> bit-same
    }
}

__global__ __launch_bounds__(BLOCK)
void EvolvedNet_80032420593868_kernel(const float* __restrict__ x,
                                      const int*   __restrict__ soff,
                                      const int*   __restrict__ doff,
                                      const float* __restrict__ wk,
                                      float*       __restrict__ out) {
    // vals[node*BLOCK + tid]: per-thread f32x2 column (2 batch elements).
    // Wave-uniform node index -> lanes hit consecutive bank pairs, conflict-free.
    __shared__ f32x2 vals[N_NODES * BLOCK];

    const int tid = threadIdx.x;
    const int b0  = blockIdx.x * TILE + tid * 2;   // adjacent element pair

    // init: inputs into nodes 0..7 (coalesced 8B loads), zeros elsewhere.
#pragma unroll
    for (int n = 0; n < N_INPUTS; ++n)
        vals[n * BLOCK + tid] = *(const f32x2*)&x[n * BATCH + b0];
#pragma unroll
    for (int n = N_INPUTS; n < N_NODES; ++n)
        vals[n * BLOCK + tid] = (f32x2)(0.0f, 0.0f);

    // No __syncthreads needed: each thread touches only its own column;
    // per-thread LDS ops are ordered by the in-order DS pipe.

    for (int sweep = 0; sweep < N_NODES; ++sweep) {
#pragma unroll 8
        for (int e = 0; e < N_EDGES; ++e) {
            const int   so = __builtin_amdgcn_readfirstlane(soff[e]);
            const int   dd = __builtin_amdgcn_readfirstlane(doff[e]);
            const float wv = sread_f(&wk[e]);

            const f32x2 v = vals[so + tid];
            f32x2 a; a.x = v.x * wv; a.y = v.y * wv;            // pk_mul
            f32x2 u;
            u.x = __builtin_amdgcn_exp2f(a.x);
            u.y = __builtin_amdgcn_exp2f(a.y);
            f32x2 s1; s1.x = 1.0f + u.x; s1.y = 1.0f + u.y;     // pk_add
            f32x2 r;
            r.x = __builtin_amdgcn_rcpf(s1.x);
            r.y = __builtin_amdgcn_rcpf(s1.y);
            f32x2 t; t.x = 1.0f - 2.0f * r.x;                   // contracts to fma
            t.y = 1.0f - 2.0f * r.y;

            f32x2 dv = vals[dd + tid];
            dv.x += t.x; dv.y += t.y;                           // pk_add
            vals[dd + tid] = dv;       // sequential semantics: program order
        }
    }

    // outputs: tanh(vals[28..31]); out is [N_OUTPUTS][BATCH] flat, 8B stores.
#pragma unroll
    for (int o = 0; o < N_OUTPUTS; ++o) {
        const f32x2 v = vals[(N_NODES - N_OUTPUTS + o) * BLOCK + tid];
        f32x2 t;
        {
            const float ax = v.x * TWO_LOG2E;
            const float ay = v.y * TWO_LOG2E;
            t.x = 1.0f - 2.0f * __builtin_amdgcn_rcpf(1.0f + __builtin_amdgcn_exp2f(ax));
            t.y = 1.0f - 2.0f * __builtin_amdgcn_rcpf(1.0f + __builtin_amdgcn_exp2f(ay));
        }
        *(f32x2*)&out[o * BATCH + b0] = t;
    }
}

extern "C" void kernel_launch(void* const* d_in, const int* in_sizes, int n_in,
                              void* d_out, int out_size, void* d_ws, size_t ws_size,
                              hipStream_t stream) {
    const float* x   = (const float*)d_in[0];
    const float* w   = (const float*)d_in[1];
    const int*   src = (const int*)d_in[2];
    const int*   dst = (const int*)d_in[3];
    float*       out = (float*)d_out;

    // d_ws layout: soff[128] | doff[128] | wk[128]  (1.5 KB)
    int*   soff = (int*)d_ws;
    int*   doff = soff + N_EDGES;
    float* wkp  = (float*)(doff + N_EDGES);

    EvolvedNet_prep<<<1, 128, 0, stream>>>(w, src, dst, soff, doff, wkp);

    const int grid = BATCH / TILE;   // 4096 blocks, exact
    EvolvedNet_80032420593868_kernel<<<grid, BLOCK, 0, stream>>>(x, soff, doff, wkp, out);
}